// Round 2
// baseline (719.879 us; speedup 1.0000x reference)
//
#include <hip/hip_runtime.h>

// AttentionRNN: B=64, NUM=8, TC=64, H=128. bn=512 sequences.
// 256 blocks x 512 threads, 2 seqs/block, 64-step scan.
// GRU weights (2x[128][384] fp32 = 393KB) register-resident: each thread owns
// 3 half-columns (64 floats each) = 192 VGPRs. uproj in LDS transposed.

// LDS offsets (floats)
#define OFF_UPT   0        // [2][64][128] uproj^T: ((seq*64+s)*128+hh)
#define OFF_ATTW  16384    // [128][64]
#define OFF_U     24576    // [64][64] (prologue only)
#define OFF_XMRM  28672    // [mat][seq][384]
#define OFF_HST   30208    // [2][128]
#define OFF_HPP   30464    // [2][4][64]
#define OFF_HPART 30976    // [2][64]
#define OFF_XTV   31104    // [2][128]
#define OFF_VV    31360    // [64]
#define OFF_RED   31424    // [16]
#define LDS_FLOATS 31456   // ~123 KB

__global__ __launch_bounds__(512, 2)
void attn_gru_kernel(const float* __restrict__ x, const float* __restrict__ att_v,
                     const float* __restrict__ att_w, const float* __restrict__ att_u,
                     const float* __restrict__ gk, const float* __restrict__ grk,
                     const float* __restrict__ gbias, float* __restrict__ out) {
    __shared__ float lds[LDS_FLOATS];
    const int tid = threadIdx.x;
    const int bn0 = blockIdx.x * 2;

    // ---- stage U, attw, v; zero h
    for (int i = tid; i < 4096; i += 512) lds[OFF_U + i] = att_u[i];
    for (int i = tid; i < 8192; i += 512) lds[OFF_ATTW + i] = att_w[i];
    if (tid < 64) lds[OFF_VV + tid] = att_v[tid];
    if (tid < 256) lds[OFF_HST + tid] = 0.0f;
    __syncthreads();

    // ---- thread mappings
    // phase C / xtv / softmax: adjacent lanes = s-halves of same (seq,hh)
    const int cseq = tid >> 8;          // 0/1
    const int chh  = (tid >> 1) & 127;  // feature
    const int csh  = tid & 1;           // s-half
    // phase A
    const int as   = tid & 63;
    const int aq   = (tid >> 6) & 3;
    const int aseq = tid >> 8;
    // phase D: thread owns 3 half-columns; halves on adjacent lanes
    const int half = tid & 1;
    const int c0   = tid >> 1;          // 0..255

    // ---- prologue 1: uproj^T into LDS.  uproj[hh][s] = sum_t x[t,hh]*U[t,s]
    {
        float up[32];
        #pragma unroll
        for (int k = 0; k < 32; ++k) up[k] = 0.0f;
        const float* xb = x + (size_t)(bn0 + cseq) * 8192 + chh;
        const float* Ub = lds + OFF_U + csh * 32;
        #pragma unroll 4
        for (int t = 0; t < 64; ++t) {
            float xv = xb[t * 128];
            const float* Ur = Ub + t * 64;
            #pragma unroll
            for (int k = 0; k < 32; ++k) up[k] += xv * Ur[k];
        }
        #pragma unroll
        for (int k = 0; k < 32; ++k)
            lds[OFF_UPT + (cseq * 64 + csh * 32 + k) * 128 + chh] = up[k];
    }
    // sum of |v|-half for tanh identity: e_part = sv - 2*sum v/(1+e^{2x})
    float sv = 0.0f;
    #pragma unroll
    for (int k = 0; k < 32; ++k) sv += lds[OFF_VV + csh * 32 + k];

    // ---- prologue 2: register-resident GRU weights (3 half-columns/thread)
    float wreg[3][64];
    int   ivb[3];      // LDS input base (XTV for gk, HST for grk) + half*64
    int   ocol[3];     // output slot (mat*2)*384... stored as full offset base
    float biasv[3];
    #pragma unroll
    for (int i = 0; i < 3; ++i) {
        int col768 = c0 + 256 * i;
        int mat = (col768 >= 384) ? 1 : 0;
        int col = col768 - mat * 384;
        const float* wsrc = (mat ? grk : gk) + (half * 64) * 384 + col;
        #pragma unroll
        for (int k = 0; k < 64; ++k) wreg[i][k] = wsrc[k * 384];
        ivb[i]   = (mat ? OFF_HST : OFF_XTV) + half * 64;
        ocol[i]  = mat * 2 * 384 + col;      // + seq*384 at store time
        biasv[i] = gbias[mat * 384 + col];
    }
    __syncthreads();

    const float* xcol = x + (size_t)(bn0 + cseq) * 8192 + chh;

    for (int t = 0; t < 64; ++t) {
        float xv = xcol[t * 128];  // prefetch this step's x column (L2-hot)

        // ---- A: h_part partials over h-quarters
        {
            float pa = 0.0f;
            const float* hrow = lds + OFF_HST + aseq * 128 + aq * 32;
            const float* wrow = lds + OFF_ATTW + (aq * 32) * 64 + as;
            #pragma unroll 8
            for (int k = 0; k < 32; ++k) pa += hrow[k] * wrow[k * 64];
            lds[OFF_HPP + (aseq * 4 + aq) * 64 + as] = pa;
        }
        __syncthreads();
        // ---- B: reduce quarters
        if (tid < 128) {
            int sq = tid >> 6, ss = tid & 63;
            lds[OFF_HPART + sq * 64 + ss] =
                  lds[OFF_HPP + (sq * 4 + 0) * 64 + ss]
                + lds[OFF_HPP + (sq * 4 + 1) * 64 + ss]
                + lds[OFF_HPP + (sq * 4 + 2) * 64 + ss]
                + lds[OFF_HPP + (sq * 4 + 3) * 64 + ss];
        }
        __syncthreads();
        // ---- C: e = sum_s tanh(hp+up)*v over 64 s, split across lane pairs
        float den = 0.0f;
        {
            const float4* hp4 = (const float4*)(lds + OFF_HPART + cseq * 64 + csh * 32);
            const float4* vv4 = (const float4*)(lds + OFF_VV + csh * 32);
            const float*  up  = lds + OFF_UPT + (cseq * 64 + csh * 32) * 128 + chh;
            #pragma unroll
            for (int k4 = 0; k4 < 8; ++k4) {
                float4 hp = hp4[k4];
                float4 v4 = vv4[k4];
                den += v4.x * __fdividef(1.0f, __expf(2.0f * (hp.x + up[(k4 * 4 + 0) * 128])) + 1.0f);
                den += v4.y * __fdividef(1.0f, __expf(2.0f * (hp.y + up[(k4 * 4 + 1) * 128])) + 1.0f);
                den += v4.z * __fdividef(1.0f, __expf(2.0f * (hp.z + up[(k4 * 4 + 2) * 128])) + 1.0f);
                den += v4.w * __fdividef(1.0f, __expf(2.0f * (hp.w + up[(k4 * 4 + 3) * 128])) + 1.0f);
            }
        }
        float ep = sv - 2.0f * den;
        float e  = ep + __shfl_xor(ep, 1);     // full e for (cseq,chh), dup'd on pair
        // softmax over hh (|e| <= sum|v| ~ 5, no max pass needed in fp32)
        float p = __expf(e);
        float ws = p;
        #pragma unroll
        for (int off = 2; off <= 32; off <<= 1) ws += __shfl_xor(ws, off);
        if ((tid & 63) == 0) lds[OFF_RED + (tid >> 6)] = ws;  // per-wave: sum over its 32 hh
        __syncthreads();
        float denom = lds[OFF_RED + cseq * 4 + 0] + lds[OFF_RED + cseq * 4 + 1]
                    + lds[OFF_RED + cseq * 4 + 2] + lds[OFF_RED + cseq * 4 + 3];
        float a = __fdividef(p, denom);
        lds[OFF_XTV + cseq * 128 + chh] = a * xv;   // pair writes same value: benign
        __syncthreads();
        // ---- D: xm/rm via register-resident weights. acc over own 64-row half.
        #pragma unroll
        for (int i = 0; i < 3; ++i) {
            #pragma unroll
            for (int sq = 0; sq < 2; ++sq) {
                const float4* inp = (const float4*)(lds + ivb[i] + sq * 128);
                float acc = 0.0f;
                #pragma unroll
                for (int k4 = 0; k4 < 16; ++k4) {
                    float4 iv = inp[k4];
                    acc += wreg[i][k4 * 4 + 0] * iv.x;
                    acc += wreg[i][k4 * 4 + 1] * iv.y;
                    acc += wreg[i][k4 * 4 + 2] * iv.z;
                    acc += wreg[i][k4 * 4 + 3] * iv.w;
                }
                float full = acc + __shfl_xor(acc, 1);  // combine row-halves
                if (half == 0)
                    lds[OFF_XMRM + ocol[i] + sq * 384] = full + biasv[i];
            }
        }
        __syncthreads();
        // ---- E: gates + h update (256 threads)
        if (tid < 256) {
            int eseq = tid >> 7, ehh = tid & 127;
            const float* xm = lds + OFF_XMRM + (0 * 2 + eseq) * 384;
            const float* rm = lds + OFF_XMRM + (1 * 2 + eseq) * 384;
            float xz = xm[ehh], xr = xm[128 + ehh], xh = xm[256 + ehh];
            float rz = rm[ehh], rr = rm[128 + ehh], rh = rm[256 + ehh];
            float z = __fdividef(1.0f, 1.0f + __expf(-(xz + rz)));
            float r = __fdividef(1.0f, 1.0f + __expf(-(xr + rr)));
            float hc = xh + r * rh;
            hc = hc > 0.0f ? hc : 0.0f;
            float hold = lds[OFF_HST + eseq * 128 + ehh];
            lds[OFF_HST + eseq * 128 + ehh] = z * hold + (1.0f - z) * hc;
        }
        __syncthreads();
    }

    if (tid < 256) {
        int eseq = tid >> 7, ehh = tid & 127;
        out[(size_t)(bn0 + eseq) * 128 + ehh] = lds[OFF_HST + eseq * 128 + ehh];
    }
}

extern "C" void kernel_launch(void* const* d_in, const int* in_sizes, int n_in,
                              void* d_out, int out_size, void* d_ws, size_t ws_size,
                              hipStream_t stream) {
    (void)in_sizes; (void)n_in; (void)out_size; (void)d_ws; (void)ws_size;
    const float* x      = (const float*)d_in[0];
    const float* att_v  = (const float*)d_in[1];
    const float* att_w  = (const float*)d_in[2];
    const float* att_u  = (const float*)d_in[3];
    const float* gk     = (const float*)d_in[4];
    const float* grk    = (const float*)d_in[5];
    const float* gbias  = (const float*)d_in[6];
    float* out = (float*)d_out;
    hipLaunchKernelGGL(attn_gru_kernel, dim3(256), dim3(512), 0, stream,
                       x, att_v, att_w, att_u, gk, grk, gbias, out);
}